// Round 4
// baseline (1129.813 us; speedup 1.0000x reference)
//
#include <hip/hip_runtime.h>
#include <stdint.h>

// Problem constants (B,T,C,H,N) = (4,960,2048,32,64)
#define BDIM 4
#define TDIM 960
#define CDIM 2048
#define HDIM 32
#define NDIM 64
#define BT   (BDIM*TDIM)   // 3840 rows

typedef unsigned short u16;
typedef __attribute__((ext_vector_type(8))) short short8;   // 8 bf16 (4 VGPRs)
typedef __attribute__((ext_vector_type(4))) float f32x4;

__device__ __forceinline__ float b2f(u16 u){
  union{unsigned int i; float f;}x; x.i=((unsigned int)u)<<16; return x.f;
}
__device__ __forceinline__ u16 f2b(float f){
  union{float f; unsigned int i;}x; x.f=f;
  unsigned int r = x.i + 0x7fffu + ((x.i>>16)&1u);   // RNE
  return (u16)(r>>16);
}
__device__ __forceinline__ void unpack8(uint4 p, float* o){
  o[0]=b2f((u16)(p.x&0xffff)); o[1]=b2f((u16)(p.x>>16));
  o[2]=b2f((u16)(p.y&0xffff)); o[3]=b2f((u16)(p.y>>16));
  o[4]=b2f((u16)(p.z&0xffff)); o[5]=b2f((u16)(p.z>>16));
  o[6]=b2f((u16)(p.w&0xffff)); o[7]=b2f((u16)(p.w>>16));
}
__device__ __forceinline__ uint4 pack8(const float* o){
  uint4 p;
  p.x = (unsigned)f2b(o[0]) | ((unsigned)f2b(o[1])<<16);
  p.y = (unsigned)f2b(o[2]) | ((unsigned)f2b(o[3])<<16);
  p.z = (unsigned)f2b(o[4]) | ((unsigned)f2b(o[5])<<16);
  p.w = (unsigned)f2b(o[6]) | ((unsigned)f2b(o[7])<<16);
  return p;
}
__device__ __forceinline__ void ld8f(const float* p, float* o){
  float4 a = *(const float4*)p;
  float4 b = *(const float4*)(p+4);
  o[0]=a.x;o[1]=a.y;o[2]=a.z;o[3]=a.w;o[4]=b.x;o[5]=b.y;o[6]=b.z;o[7]=b.w;
}
__device__ __forceinline__ float sigm(float x){ return 1.f/(1.f+expf(-x)); }
__device__ __forceinline__ void stc(float* p, float v){ *p = v; }
__device__ __forceinline__ void stc(u16* p, float v){ *p = f2b(v); }

// ---------------------------------------------------------------------------
// 0) fp32 -> bf16 weight conversion (one 2048x2048 matrix per launch)
__global__ __launch_bounds__(256) void cvt_kernel(const float* src, u16* dst){
  size_t i = ((size_t)blockIdx.x*256 + threadIdx.x)*8;
  float v[8]; ld8f(src+i, v);
  *(uint4*)(dst+i) = pack8(v);
}

// ---------------------------------------------------------------------------
// 1) batched transpose+pad+cvt for LoRA weights (tiny: <6 MB total)
// dst[i][k] = (i<Cs && k<R) ? src[k][i] : 0   with dst dims DR x DC
struct TJob { const float* src; u16* dst; int R, Cs, DR, DC; };
struct TJobs8 { TJob j[8]; };

__global__ __launch_bounds__(256) void transpose_pad_kernel(TJobs8 jobs){
  TJob jb = jobs.j[blockIdx.z];
  int idx = blockIdx.x*256 + threadIdx.x;
  int total = jb.DR*jb.DC;
  if (idx >= total) return;
  int i = idx / jb.DC, k = idx % jb.DC;
  float v = 0.f;
  if (i < jb.Cs && k < jb.R) v = jb.src[(size_t)k*jb.Cs + i];
  jb.dst[idx] = f2b(v);
}

// ---------------------------------------------------------------------------
// 2) token-shift mixes: m = x + (x_prev - x)*coef  (6 bf16 outputs)
__global__ __launch_bounds__(256) void mix_kernel(
  const float* x,
  const float* cr, const float* cw, const float* ck,
  const float* cv, const float* ca, const float* cg,
  u16* mr, u16* mw, u16* mk, u16* mv, u16* ma, u16* mg)
{
  size_t tid = (size_t)blockIdx.x*256 + threadIdx.x;
  size_t base = tid*8;
  int c = (int)(base % CDIM);
  int row = (int)(base / CDIM);
  int t = row % TDIM;
  float xc[8], xp[8], xx[8], cf[8], o[8];
  ld8f(x+base, xc);
  if (t > 0) {
    ld8f(x+base-CDIM, xp);
  } else {
    for(int j=0;j<8;j++) xp[j]=0.f;
  }
  #pragma unroll
  for(int j=0;j<8;j++) xx[j]=xp[j]-xc[j];
#define DOMIX(CP, OP) do { ld8f(CP+c, cf); \
  _Pragma("unroll") for(int j=0;j<8;j++) o[j]=xc[j]+xx[j]*cf[j]; \
  *(uint4*)(OP+base)=pack8(o); } while(0)
  DOMIX(cr, mr); DOMIX(cw, mw); DOMIX(ck, mk);
  DOMIX(cv, mv); DOMIX(ca, ma); DOMIX(cg, mg);
#undef DOMIX
}

// ---------------------------------------------------------------------------
// 3) bf16 GEMM, C[M,N] = A[M,K] * Bt[N,K]^T  (B^T layout, m97 structure)
// 128x128 tile, BK=64, 256 threads (2x2 waves, each 64x64 = 4x4 MFMA 16x16x32)
// C store dtype templated (fp32 or bf16).
struct GemmJob {
  const u16* A; const u16* Bt; void* C;
  int nbm, nbn, K, lda, ldb, ldc;
};
struct GemmJobs { GemmJob j[4]; };

template<typename TC>
__global__ __launch_bounds__(256, 2) void gemm_bt_kernel(GemmJobs jobs){
  GemmJob jb = jobs.j[blockIdx.z];
  int bm = blockIdx.x % jb.nbm;
  int bn = blockIdx.x / jb.nbm;
  if (bn >= jb.nbn) return;
  __shared__ __attribute__((aligned(16))) u16 As[128*64];
  __shared__ __attribute__((aligned(16))) u16 Bs[128*64];
  int tid = threadIdx.x;
  int wave = tid>>6, lane = tid&63;
  int wr = wave>>1, wc = wave&1;
  f32x4 acc[4][4];
  #pragma unroll
  for(int i=0;i<4;i++)
    #pragma unroll
    for(int j=0;j<4;j++) acc[i][j] = (f32x4){0.f,0.f,0.f,0.f};
  const int rA0 = bm*128;
  const int rB0 = bn*128;
  int srow = (lane>>3);        // 0..7 row within 8-row slab
  int scol = (lane&7)*8;       // k element offset (8 bf16 = 16B)
  for (int k0=0; k0<jb.K; k0+=64){
    #pragma unroll
    for (int it=0; it<4; ++it){
      int rr = wave*32 + it*8;  // wave-uniform
      const u16* gA = jb.A + (size_t)(rA0 + rr + srow)*jb.lda + (k0 + scol);
      __builtin_amdgcn_global_load_lds((const __attribute__((address_space(1))) void*)gA,
          (__attribute__((address_space(3))) void*)&As[rr*64], 16, 0, 0);
      const u16* gB = jb.Bt + (size_t)(rB0 + rr + srow)*jb.ldb + (k0 + scol);
      __builtin_amdgcn_global_load_lds((const __attribute__((address_space(1))) void*)gB,
          (__attribute__((address_space(3))) void*)&Bs[rr*64], 16, 0, 0);
    }
    __syncthreads();   // compiler emits vmcnt(0) drain before s_barrier
    #pragma unroll
    for (int kc=0; kc<2; ++kc){
      short8 af[4], bfr[4];
      int ko = kc*32 + (lane>>4)*8;
      #pragma unroll
      for (int mi=0; mi<4; ++mi)
        af[mi] = *(const short8*)&As[(wr*64 + mi*16 + (lane&15))*64 + ko];
      #pragma unroll
      for (int ni=0; ni<4; ++ni)
        bfr[ni] = *(const short8*)&Bs[(wc*64 + ni*16 + (lane&15))*64 + ko];
      #pragma unroll
      for (int mi=0; mi<4; ++mi)
        #pragma unroll
        for (int ni=0; ni<4; ++ni)
          acc[mi][ni] = __builtin_amdgcn_mfma_f32_16x16x32_bf16(af[mi], bfr[ni], acc[mi][ni], 0, 0, 0);
    }
    __syncthreads();
  }
  // epilogue: C/D layout col=lane&15, row=(lane>>4)*4+reg  [m89/m91 verified]
  TC* C = (TC*)jb.C;
  int cn = (lane&15);
  int rq = (lane>>4)*4;
  #pragma unroll
  for (int mi=0; mi<4; ++mi){
    #pragma unroll
    for (int ni=0; ni<4; ++ni){
      int col = rB0 + wc*64 + ni*16 + cn;
      int row = rA0 + wr*64 + mi*16 + rq;
      #pragma unroll
      for (int e=0; e<4; ++e)
        stc(&C[(size_t)(row+e)*jb.ldc + col], acc[mi][ni][e]);
    }
  }
}

// ---------------------------------------------------------------------------
// 4) mid-LoRA activations: tanh on hw, sigmoid on hg (pads stay 0 -> tanh(0)=0)
__global__ __launch_bounds__(256) void act_kernel(u16* hw, u16* hg){
  int idx = blockIdx.x*256 + threadIdx.x;
  if (blockIdx.z==0){ if (idx < BT*128) hw[idx] = f2b(tanhf(b2f(hw[idx]))); }
  else              { if (idx < BT*256) hg[idx] = f2b(sigm(b2f(hg[idx]))); }
}

// ---------------------------------------------------------------------------
// 5) post-GEMM elementwise: w/a/v finals, kk normalize, k scale, scan inputs
__global__ __launch_bounds__(256) void post_kernel(
  const u16* kbuf, const u16* vraw, const float* vfirst,
  const u16* wl, const u16* al, const u16* vl,
  const float* w0, const float* a0, const float* v0,
  const float* kkc, const float* kac,
  float* wout, u16* ks, u16* vs, u16* as_, u16* bs)
{
  int row = blockIdx.x, tid = threadIdx.x;
  int c = tid*8;
  size_t base = (size_t)row*CDIM + c;
  float kf[8], vr[8], vf[8], wlf[8], alf[8], vlf[8], w0f[8], a0f[8], v0f[8], kkf[8], kaf[8];
  unpack8(*(const uint4*)(kbuf+base), kf);
  unpack8(*(const uint4*)(vraw+base), vr);
  ld8f(vfirst+base, vf);
  unpack8(*(const uint4*)(wl+base), wlf);
  unpack8(*(const uint4*)(al+base), alf);
  unpack8(*(const uint4*)(vl+base), vlf);
  ld8f(w0+c, w0f);
  ld8f(a0+c, a0f);
  ld8f(v0+c, v0f);
  ld8f(kkc+c, kkf);
  ld8f(kac+c, kaf);
  float wv[8], av[8], vv[8], kkr[8], kfin[8], asv[8], bsv[8];
  float ssq = 0.f;
  #pragma unroll
  for (int j=0;j<8;j++){
    wv[j]  = -log1pf(expf(-(w0f[j]+wlf[j]))) - 0.5f;         // -softplus(-z)-0.5
    av[j]  = sigm(a0f[j]+alf[j]);
    vv[j]  = vr[j] + (vf[j]-vr[j])*sigm(v0f[j]+vlf[j]);
    kkr[j] = kf[j]*kkf[j];
    ssq   += kkr[j]*kkr[j];
    kfin[j]= kf[j]*(1.f + (av[j]-1.f)*kaf[j]);
  }
  // head = 8 consecutive lanes (thread covers 8 contiguous c, head = 64 c)
  ssq += __shfl_xor(ssq,1); ssq += __shfl_xor(ssq,2); ssq += __shfl_xor(ssq,4);
  float inv = 1.f/fmaxf(sqrtf(ssq), 1e-12f);
  #pragma unroll
  for (int j=0;j<8;j++){ float kkn = kkr[j]*inv; asv[j] = -kkn; bsv[j] = kkn*av[j]; }
  *(float4*)(wout+base)   = make_float4(wv[0],wv[1],wv[2],wv[3]);
  *(float4*)(wout+base+4) = make_float4(wv[4],wv[5],wv[6],wv[7]);
  *(uint4*)(ks+base)  = pack8(kfin);
  *(uint4*)(vs+base)  = pack8(vv);
  *(uint4*)(as_+base) = pack8(asv);
  *(uint4*)(bs+base)  = pack8(bsv);
}

// ---------------------------------------------------------------------------
// 6) the linear recurrence. One block per (b,h); thread (i=tid>>2, jg=tid&3)
// holds S[i][jg*16 .. jg*16+15] in fp32 registers. 4 steps staged per barrier.
__global__ __launch_bounds__(256) void scan_kernel(
  const float* wdec, const u16* qb, const u16* kb, const u16* vb,
  const u16* ab, const u16* bb, float* yb)
{
  int bh = blockIdx.x;
  int b = bh >> 5, h = bh & 31;
  int tid = threadIdx.x;
  int jg = tid & 3, ii = tid >> 2;
  __shared__ float sw[256], sq[256], sk[256], sv[256], sa[256], sb[256];
  float S[16];
  #pragma unroll
  for (int m=0;m<16;m++) S[m]=0.f;
  size_t hbase = ((size_t)b*TDIM)*CDIM + (size_t)h*NDIM;
  int le = tid>>6, ee = tid&63;
  for (int t0=0; t0<TDIM; t0+=4){
    size_t g = hbase + (size_t)(t0+le)*CDIM + ee;
    int sidx = le*64+ee;
    sw[sidx] = expf(-expf(wdec[g]));   // decay (fp32 path: compounding-sensitive)
    sq[sidx] = b2f(qb[g]);
    sk[sidx] = b2f(kb[g]);
    sv[sidx] = b2f(vb[g]);
    sa[sidx] = b2f(ab[g]);
    sb[sidx] = b2f(bb[g]);
    __syncthreads();
    #pragma unroll
    for (int s=0; s<4; ++s){
      const float* pw = &sw[s*64 + jg*16];
      const float* pq = &sq[s*64 + jg*16];
      const float* pk = &sk[s*64 + jg*16];
      const float* pa = &sa[s*64 + jg*16];
      const float* pb = &sb[s*64 + jg*16];
      float vi = sv[s*64 + ii];
      float sap = 0.f;
      #pragma unroll
      for (int m4=0; m4<4; ++m4){
        f32x4 a4 = *(const f32x4*)&pa[m4*4];
        sap += S[m4*4+0]*a4[0] + S[m4*4+1]*a4[1] + S[m4*4+2]*a4[2] + S[m4*4+3]*a4[3];
      }
      sap += __shfl_xor(sap, 1);
      sap += __shfl_xor(sap, 2);     // full sum over the 4 jg lanes
      float yp = 0.f;
      #pragma unroll
      for (int m4=0; m4<4; ++m4){
        f32x4 w4 = *(const f32x4*)&pw[m4*4];
        f32x4 k4 = *(const f32x4*)&pk[m4*4];
        f32x4 b4 = *(const f32x4*)&pb[m4*4];
        f32x4 q4 = *(const f32x4*)&pq[m4*4];
        #pragma unroll
        for (int e=0; e<4; ++e){
          int m = m4*4+e;
          float sm = S[m]*w4[e] + sap*b4[e] + vi*k4[e];
          S[m] = sm;
          yp += sm*q4[e];
        }
      }
      yp += __shfl_xor(yp, 1);
      yp += __shfl_xor(yp, 2);
      if (jg==0) yb[hbase + (size_t)(t0+s)*CDIM + ii] = yp;
    }
    __syncthreads();
  }
}

// ---------------------------------------------------------------------------
// 7) GroupNorm + bonus term + *g  -> bf16 YG (input of the final GEMM)
__global__ __launch_bounds__(256) void final_kernel(
  const float* yb, const u16* rb, const u16* ks, const u16* vs,
  const float* rk, const float* lnw, const float* lnb, const u16* gl, u16* yg)
{
  int row = blockIdx.x, tid = threadIdx.x;
  int c = tid*8;
  size_t base = (size_t)row*CDIM + c;
  float y[8], rf[8], kf[8], vf[8], rkf[8], lw[8], lb[8], gf[8];
  ld8f(yb+base, y);
  unpack8(*(const uint4*)(rb+base), rf);
  unpack8(*(const uint4*)(ks+base), kf);
  unpack8(*(const uint4*)(vs+base), vf);
  ld8f(rk+c,  rkf);   // r_k is [H*N]=[C] flat
  ld8f(lnw+c, lw);
  ld8f(lnb+c, lb);
  unpack8(*(const uint4*)(gl+base), gf);
  float sy=0.f, syy=0.f, coef=0.f;
  #pragma unroll
  for (int j=0;j<8;j++){ sy+=y[j]; syy+=y[j]*y[j]; coef += rf[j]*kf[j]*rkf[j]; }
  sy  += __shfl_xor(sy,1);  sy  += __shfl_xor(sy,2);  sy  += __shfl_xor(sy,4);
  syy += __shfl_xor(syy,1); syy += __shfl_xor(syy,2); syy += __shfl_xor(syy,4);
  coef+= __shfl_xor(coef,1);coef+= __shfl_xor(coef,2);coef+= __shfl_xor(coef,4);
  float mu  = sy*(1.f/64.f);
  float var = syy*(1.f/64.f) - mu*mu;
  float rs  = rsqrtf(var + 6.4e-4f);    // EPS_GN = 1e-5*64
  float o[8];
  #pragma unroll
  for (int j=0;j<8;j++)
    o[j] = (((y[j]-mu)*rs)*lw[j] + lb[j] + coef*vf[j]) * gf[j];
  *(uint4*)(yg+base) = pack8(o);
}

// ---------------------------------------------------------------------------
extern "C" void kernel_launch(void* const* d_in, const int* in_sizes, int n_in,
                              void* d_out, int out_size, void* d_ws, size_t ws_size,
                              hipStream_t stream)
{
  const float* x      = (const float*)d_in[0];
  const float* vfirst = (const float*)d_in[1];
  const float* c_r = (const float*)d_in[2];
  const float* c_w = (const float*)d_in[3];
  const float* c_k = (const float*)d_in[4];
  const float* c_v = (const float*)d_in[5];
  const float* c_a = (const float*)d_in[6];
  const float* c_g = (const float*)d_in[7];
  const float* w0i = (const float*)d_in[8];
  const float* w1i = (const float*)d_in[9];
  const float* w2i = (const float*)d_in[10];
  const float* a0i = (const float*)d_in[11];
  const float* a1i = (const float*)d_in[12];
  const float* a2i = (const float*)d_in[13];
  const float* v0i = (const float*)d_in[14];
  const float* v1i = (const float*)d_in[15];
  const float* v2i = (const float*)d_in[16];
  const float* g1i = (const float*)d_in[17];
  const float* g2i = (const float*)d_in[18];
  const float* kki = (const float*)d_in[19];
  const float* kai = (const float*)d_in[20];
  const float* rki = (const float*)d_in[21];
  const float* Wr  = (const float*)d_in[22];
  const float* Wk  = (const float*)d_in[23];
  const float* Wv  = (const float*)d_in[24];
  const float* Wo  = (const float*)d_in[25];
  const float* lnw = (const float*)d_in[26];
  const float* lnb = (const float*)d_in[27];

  char* ws = (char*)d_ws;
  const size_t S2 = (size_t)BT*CDIM*2;    // bf16 [BT,C] plane = 15,728,640 B
  // bf16 mix planes [0, 6*S2)  (later aliased by scan inputs)
  u16* MIXR = (u16*)(ws + 0*S2);
  u16* MIXW = (u16*)(ws + 1*S2);
  u16* MIXK = (u16*)(ws + 2*S2);
  u16* MIXV = (u16*)(ws + 3*S2);
  u16* MIXA = (u16*)(ws + 4*S2);
  u16* MIXG = (u16*)(ws + 5*S2);
  // bf16 projection outputs
  u16* RBUF = (u16*)(ws + 6*S2);
  u16* KBUF = (u16*)(ws + 7*S2);
  u16* VRAW = (u16*)(ws + 8*S2);
  // single reusable bf16 weight slot (Wr -> Wk -> Wv -> Wo, stream-ordered)
  char* WB = ws + 9*S2;
  u16* WSLOT = (u16*)WB;            // 2048*2048*2 = 8,388,608 B
  char* WT = WB + 8388608;
  u16* W1T = (u16*)(WT + 0);        // [128,2048]
  u16* A1T = (u16*)(WT + 524288);
  u16* V1T = (u16*)(WT + 1048576);
  u16* G1T = (u16*)(WT + 1572864);  // [256,2048]
  u16* W2T = (u16*)(WT + 2621440);  // [2048,128]
  u16* A2T = (u16*)(WT + 3145728);
  u16* V2T = (u16*)(WT + 3670016);
  u16* G2T = (u16*)(WT + 4194304);  // [2048,256]
  char* HB = WT + 5242880;
  u16* HW = (u16*)(HB + 0);         // [BT,128]
  u16* HA = (u16*)(HB + 983040);
  u16* HV = (u16*)(HB + 1966080);
  u16* HG = (u16*)(HB + 2949120);   // [BT,256]
  char* L2 = HB + 4915200;
  u16* WL = (u16*)(L2 + 0*S2);
  u16* AL = (u16*)(L2 + 1*S2);
  u16* VL = (u16*)(L2 + 2*S2);
  u16* GL = (u16*)(L2 + 3*S2);      // ws end = L2 + 4*S2 = 223,019,008 B (~212.7 MiB)
  // aliases (producers strictly after last consumer of the dead buffers):
  float* WDEC = (float*)(ws + 0*S2);    // fp32 over MIXR+MIXW
  u16* KS = (u16*)(ws + 2*S2);          // over MIXK
  u16* VS = (u16*)(ws + 3*S2);          // over MIXV
  u16* AS = (u16*)(ws + 4*S2);          // over MIXA
  u16* BS = (u16*)(ws + 5*S2);          // over MIXG
  float* YBUF = (float*)(L2 + 0*S2);    // fp32 over WL+AL
  u16* YG = (u16*)(L2 + 2*S2);          // over VL
  (void)in_sizes; (void)n_in; (void)out_size; (void)ws_size;

  // 1) transpose+pad+cvt LoRA weights
  TJobs8 tj;
  tj.j[0] = (TJob){w1i, W1T, 2048,  96, 128, 2048};
  tj.j[1] = (TJob){a1i, A1T, 2048,  96, 128, 2048};
  tj.j[2] = (TJob){v1i, V1T, 2048,  64, 128, 2048};
  tj.j[3] = (TJob){g1i, G1T, 2048, 256, 256, 2048};
  tj.j[4] = (TJob){w2i, W2T,   96, 2048, 2048, 128};
  tj.j[5] = (TJob){a2i, A2T,   96, 2048, 2048, 128};
  tj.j[6] = (TJob){v2i, V2T,   64, 2048, 2048, 128};
  tj.j[7] = (TJob){g2i, G2T,  256, 2048, 2048, 256};
  transpose_pad_kernel<<<dim3(2048,1,8), 256, 0, stream>>>(tj);

  // 2) token-shift mixes (fp32 in, bf16 out)
  mix_kernel<<<dim3(BT*CDIM/8/256), 256, 0, stream>>>(
      x, c_r, c_w, c_k, c_v, c_a, c_g, MIXR, MIXW, MIXK, MIXV, MIXA, MIXG);

  // 3) big projections r,k,v (bf16 C), weight slot reused via stream ordering
  {
    GemmJobs gj;
    cvt_kernel<<<dim3(2048), 256, 0, stream>>>(Wr, WSLOT);
    gj.j[0] = (GemmJob){MIXR, WSLOT, RBUF, 30, 16, 2048, 2048, 2048, 2048};
    gj.j[1] = gj.j[0]; gj.j[2] = gj.j[0]; gj.j[3] = gj.j[0];
    gemm_bt_kernel<u16><<<dim3(480,1,1), 256, 0, stream>>>(gj);
    cvt_kernel<<<dim3(2048), 256, 0, stream>>>(Wk, WSLOT);
    gj.j[0] = (GemmJob){MIXK, WSLOT, KBUF, 30, 16, 2048, 2048, 2048, 2048};
    gemm_bt_kernel<u16><<<dim3(480,1,1), 256, 0, stream>>>(gj);
    cvt_kernel<<<dim3(2048), 256, 0, stream>>>(Wv, WSLOT);
    gj.j[0] = (GemmJob){MIXV, WSLOT, VRAW, 30, 16, 2048, 2048, 2048, 2048};
    gemm_bt_kernel<u16><<<dim3(480,1,1), 256, 0, stream>>>(gj);
  }

  // 4) LoRA first halves (bf16 C)
  GemmJobs lj1;
  lj1.j[0] = (GemmJob){MIXW, W1T, HW, 30, 1, 2048, 2048, 2048, 128};
  lj1.j[1] = (GemmJob){MIXA, A1T, HA, 30, 1, 2048, 2048, 2048, 128};
  lj1.j[2] = (GemmJob){MIXV, V1T, HV, 30, 1, 2048, 2048, 2048, 128};
  lj1.j[3] = (GemmJob){MIXG, G1T, HG, 30, 2, 2048, 2048, 2048, 256};
  gemm_bt_kernel<u16><<<dim3(60,1,4), 256, 0, stream>>>(lj1);

  // 5) mid activations
  act_kernel<<<dim3(3840,1,2), 256, 0, stream>>>(HW, HG);

  // 6) LoRA second halves (bf16 C)
  GemmJobs lj2;
  lj2.j[0] = (GemmJob){HW, W2T, WL, 30, 16, 128, 128, 128, 2048};
  lj2.j[1] = (GemmJob){HA, A2T, AL, 30, 16, 128, 128, 128, 2048};
  lj2.j[2] = (GemmJob){HV, V2T, VL, 30, 16, 128, 128, 128, 2048};
  lj2.j[3] = (GemmJob){HG, G2T, GL, 30, 16, 256, 256, 256, 2048};
  gemm_bt_kernel<u16><<<dim3(480,1,4), 256, 0, stream>>>(lj2);

  // 7) post elementwise -> scan inputs (write into dead mix planes)
  post_kernel<<<dim3(BT), 256, 0, stream>>>(
      KBUF, VRAW, vfirst, WL, AL, VL, w0i, a0i, v0i, kki, kai,
      WDEC, KS, VS, AS, BS);

  // 8) recurrence
  scan_kernel<<<dim3(BDIM*HDIM), 256, 0, stream>>>(
      WDEC, RBUF, KS, VS, AS, BS, YBUF);

  // 9) GroupNorm + bonus + *g -> bf16 YG
  final_kernel<<<dim3(BT), 256, 0, stream>>>(
      YBUF, RBUF, KS, VS, rki, lnw, lnb, GL, YG);

  // 10) output projection (fp32 C = d_out)
  cvt_kernel<<<dim3(2048), 256, 0, stream>>>(Wo, WSLOT);
  GemmJobs oj;
  oj.j[0] = (GemmJob){YG, WSLOT, d_out, 30, 16, 2048, 2048, 2048, 2048};
  oj.j[1] = oj.j[0]; oj.j[2] = oj.j[0]; oj.j[3] = oj.j[0];
  gemm_bt_kernel<float><<<dim3(480,1,1), 256, 0, stream>>>(oj);
}

// Round 5
// 917.710 us; speedup vs baseline: 1.2311x; 1.2311x over previous
//
#include <hip/hip_runtime.h>
#include <stdint.h>

// Problem constants (B,T,C,H,N) = (4,960,2048,32,64)
#define BDIM 4
#define TDIM 960
#define CDIM 2048
#define HDIM 32
#define NDIM 64
#define BT   (BDIM*TDIM)   // 3840 rows

typedef unsigned short u16;
typedef __attribute__((ext_vector_type(8))) short short8;   // 8 bf16 (4 VGPRs)
typedef __attribute__((ext_vector_type(4))) float f32x4;

__device__ __forceinline__ float b2f(u16 u){
  union{unsigned int i; float f;}x; x.i=((unsigned int)u)<<16; return x.f;
}
__device__ __forceinline__ u16 f2b(float f){
  union{float f; unsigned int i;}x; x.f=f;
  unsigned int r = x.i + 0x7fffu + ((x.i>>16)&1u);   // RNE
  return (u16)(r>>16);
}
__device__ __forceinline__ void unpack8(uint4 p, float* o){
  o[0]=b2f((u16)(p.x&0xffff)); o[1]=b2f((u16)(p.x>>16));
  o[2]=b2f((u16)(p.y&0xffff)); o[3]=b2f((u16)(p.y>>16));
  o[4]=b2f((u16)(p.z&0xffff)); o[5]=b2f((u16)(p.z>>16));
  o[6]=b2f((u16)(p.w&0xffff)); o[7]=b2f((u16)(p.w>>16));
}
__device__ __forceinline__ uint4 pack8(const float* o){
  uint4 p;
  p.x = (unsigned)f2b(o[0]) | ((unsigned)f2b(o[1])<<16);
  p.y = (unsigned)f2b(o[2]) | ((unsigned)f2b(o[3])<<16);
  p.z = (unsigned)f2b(o[4]) | ((unsigned)f2b(o[5])<<16);
  p.w = (unsigned)f2b(o[6]) | ((unsigned)f2b(o[7])<<16);
  return p;
}
__device__ __forceinline__ void ld8f(const float* p, float* o){
  float4 a = *(const float4*)p;
  float4 b = *(const float4*)(p+4);
  o[0]=a.x;o[1]=a.y;o[2]=a.z;o[3]=a.w;o[4]=b.x;o[5]=b.y;o[6]=b.z;o[7]=b.w;
}
__device__ __forceinline__ float sigm(float x){ return 1.f/(1.f+expf(-x)); }
__device__ __forceinline__ void stc(float* p, float v){ *p = v; }
__device__ __forceinline__ void stc(u16* p, float v){ *p = f2b(v); }

// ---------------------------------------------------------------------------
// 0) fp32 -> bf16 weight conversion (one 2048x2048 matrix per launch)
__global__ __launch_bounds__(256) void cvt_kernel(const float* src, u16* dst){
  size_t i = ((size_t)blockIdx.x*256 + threadIdx.x)*8;
  float v[8]; ld8f(src+i, v);
  *(uint4*)(dst+i) = pack8(v);
}

// ---------------------------------------------------------------------------
// 1) batched transpose+pad+cvt for LoRA weights (tiny: <6 MB total)
// dst[i][k] = (i<Cs && k<R) ? src[k][i] : 0   with dst dims DR x DC
struct TJob { const float* src; u16* dst; int R, Cs, DR, DC; };
struct TJobs8 { TJob j[8]; };

__global__ __launch_bounds__(256) void transpose_pad_kernel(TJobs8 jobs){
  TJob jb = jobs.j[blockIdx.z];
  int idx = blockIdx.x*256 + threadIdx.x;
  int total = jb.DR*jb.DC;
  if (idx >= total) return;
  int i = idx / jb.DC, k = idx % jb.DC;
  float v = 0.f;
  if (i < jb.Cs && k < jb.R) v = jb.src[(size_t)k*jb.Cs + i];
  jb.dst[idx] = f2b(v);
}

// ---------------------------------------------------------------------------
// 2) token-shift mixes: m = x + (x_prev - x)*coef  (6 bf16 outputs)
__global__ __launch_bounds__(256) void mix_kernel(
  const float* x,
  const float* cr, const float* cw, const float* ck,
  const float* cv, const float* ca, const float* cg,
  u16* mr, u16* mw, u16* mk, u16* mv, u16* ma, u16* mg)
{
  size_t tid = (size_t)blockIdx.x*256 + threadIdx.x;
  size_t base = tid*8;
  int c = (int)(base % CDIM);
  int row = (int)(base / CDIM);
  int t = row % TDIM;
  float xc[8], xp[8], xx[8], cf[8], o[8];
  ld8f(x+base, xc);
  if (t > 0) {
    ld8f(x+base-CDIM, xp);
  } else {
    for(int j=0;j<8;j++) xp[j]=0.f;
  }
  #pragma unroll
  for(int j=0;j<8;j++) xx[j]=xp[j]-xc[j];
#define DOMIX(CP, OP) do { ld8f(CP+c, cf); \
  _Pragma("unroll") for(int j=0;j<8;j++) o[j]=xc[j]+xx[j]*cf[j]; \
  *(uint4*)(OP+base)=pack8(o); } while(0)
  DOMIX(cr, mr); DOMIX(cw, mw); DOMIX(ck, mk);
  DOMIX(cv, mv); DOMIX(ca, ma); DOMIX(cg, mg);
#undef DOMIX
}

// ---------------------------------------------------------------------------
// 3) bf16 GEMM, C[M,N] = A[M,K] * Bt[N,K]^T  (B^T layout, m97 structure)
// 128x128 tile, BK=64, 256 threads (2x2 waves, each 64x64 = 4x4 MFMA 16x16x32)
// C store dtype templated (fp32 or bf16).
struct GemmJob {
  const u16* A; const u16* Bt; void* C;
  int nbm, nbn, K, lda, ldb, ldc;
};
struct GemmJobs { GemmJob j[4]; };

template<typename TC>
__global__ __launch_bounds__(256, 2) void gemm_bt_kernel(GemmJobs jobs){
  GemmJob jb = jobs.j[blockIdx.z];
  int bm = blockIdx.x % jb.nbm;
  int bn = blockIdx.x / jb.nbm;
  if (bn >= jb.nbn) return;
  __shared__ __attribute__((aligned(16))) u16 As[128*64];
  __shared__ __attribute__((aligned(16))) u16 Bs[128*64];
  int tid = threadIdx.x;
  int wave = tid>>6, lane = tid&63;
  int wr = wave>>1, wc = wave&1;
  f32x4 acc[4][4];
  #pragma unroll
  for(int i=0;i<4;i++)
    #pragma unroll
    for(int j=0;j<4;j++) acc[i][j] = (f32x4){0.f,0.f,0.f,0.f};
  const int rA0 = bm*128;
  const int rB0 = bn*128;
  int srow = (lane>>3);        // 0..7 row within 8-row slab
  int scol = (lane&7)*8;       // k element offset (8 bf16 = 16B)
  for (int k0=0; k0<jb.K; k0+=64){
    #pragma unroll
    for (int it=0; it<4; ++it){
      int rr = wave*32 + it*8;  // wave-uniform
      const u16* gA = jb.A + (size_t)(rA0 + rr + srow)*jb.lda + (k0 + scol);
      __builtin_amdgcn_global_load_lds((const __attribute__((address_space(1))) void*)gA,
          (__attribute__((address_space(3))) void*)&As[rr*64], 16, 0, 0);
      const u16* gB = jb.Bt + (size_t)(rB0 + rr + srow)*jb.ldb + (k0 + scol);
      __builtin_amdgcn_global_load_lds((const __attribute__((address_space(1))) void*)gB,
          (__attribute__((address_space(3))) void*)&Bs[rr*64], 16, 0, 0);
    }
    __syncthreads();   // compiler emits vmcnt(0) drain before s_barrier
    #pragma unroll
    for (int kc=0; kc<2; ++kc){
      short8 af[4], bfr[4];
      int ko = kc*32 + (lane>>4)*8;
      #pragma unroll
      for (int mi=0; mi<4; ++mi)
        af[mi] = *(const short8*)&As[(wr*64 + mi*16 + (lane&15))*64 + ko];
      #pragma unroll
      for (int ni=0; ni<4; ++ni)
        bfr[ni] = *(const short8*)&Bs[(wc*64 + ni*16 + (lane&15))*64 + ko];
      #pragma unroll
      for (int mi=0; mi<4; ++mi)
        #pragma unroll
        for (int ni=0; ni<4; ++ni)
          acc[mi][ni] = __builtin_amdgcn_mfma_f32_16x16x32_bf16(af[mi], bfr[ni], acc[mi][ni], 0, 0, 0);
    }
    __syncthreads();
  }
  // epilogue: C/D layout col=lane&15, row=(lane>>4)*4+reg  [m89/m91 verified]
  TC* C = (TC*)jb.C;
  int cn = (lane&15);
  int rq = (lane>>4)*4;
  #pragma unroll
  for (int mi=0; mi<4; ++mi){
    #pragma unroll
    for (int ni=0; ni<4; ++ni){
      int col = rB0 + wc*64 + ni*16 + cn;
      int row = rA0 + wr*64 + mi*16 + rq;
      #pragma unroll
      for (int e=0; e<4; ++e)
        stc(&C[(size_t)(row+e)*jb.ldc + col], acc[mi][ni][e]);
    }
  }
}

// ---------------------------------------------------------------------------
// 4) mid-LoRA activations: tanh on hw, sigmoid on hg (pads stay 0 -> tanh(0)=0)
__global__ __launch_bounds__(256) void act_kernel(u16* hw, u16* hg){
  int idx = blockIdx.x*256 + threadIdx.x;
  if (blockIdx.z==0){ if (idx < BT*128) hw[idx] = f2b(tanhf(b2f(hw[idx]))); }
  else              { if (idx < BT*256) hg[idx] = f2b(sigm(b2f(hg[idx]))); }
}

// ---------------------------------------------------------------------------
// 5) post-GEMM elementwise: w decay, a/v finals, kk normalize, k scale
// NOTE: now stores DECAY = exp(-exp(w_raw)) in fp32 (moves 2 expf out of the
// serial scan loop into this parallel kernel).
__global__ __launch_bounds__(256) void post_kernel(
  const u16* kbuf, const u16* vraw, const float* vfirst,
  const u16* wl, const u16* al, const u16* vl,
  const float* w0, const float* a0, const float* v0,
  const float* kkc, const float* kac,
  float* dout, u16* ks, u16* vs, u16* as_, u16* bs)
{
  int row = blockIdx.x, tid = threadIdx.x;
  int c = tid*8;
  size_t base = (size_t)row*CDIM + c;
  float kf[8], vr[8], vf[8], wlf[8], alf[8], vlf[8], w0f[8], a0f[8], v0f[8], kkf[8], kaf[8];
  unpack8(*(const uint4*)(kbuf+base), kf);
  unpack8(*(const uint4*)(vraw+base), vr);
  ld8f(vfirst+base, vf);
  unpack8(*(const uint4*)(wl+base), wlf);
  unpack8(*(const uint4*)(al+base), alf);
  unpack8(*(const uint4*)(vl+base), vlf);
  ld8f(w0+c, w0f);
  ld8f(a0+c, a0f);
  ld8f(v0+c, v0f);
  ld8f(kkc+c, kkf);
  ld8f(kac+c, kaf);
  float dv[8], av[8], vv[8], kkr[8], kfin[8], asv[8], bsv[8];
  float ssq = 0.f;
  #pragma unroll
  for (int j=0;j<8;j++){
    float wv = -log1pf(expf(-(w0f[j]+wlf[j]))) - 0.5f;       // -softplus(-z)-0.5
    dv[j]  = expf(-expf(wv));                                // decay
    av[j]  = sigm(a0f[j]+alf[j]);
    vv[j]  = vr[j] + (vf[j]-vr[j])*sigm(v0f[j]+vlf[j]);
    kkr[j] = kf[j]*kkf[j];
    ssq   += kkr[j]*kkr[j];
    kfin[j]= kf[j]*(1.f + (av[j]-1.f)*kaf[j]);
  }
  // head = 8 consecutive lanes (thread covers 8 contiguous c, head = 64 c)
  ssq += __shfl_xor(ssq,1); ssq += __shfl_xor(ssq,2); ssq += __shfl_xor(ssq,4);
  float inv = 1.f/fmaxf(sqrtf(ssq), 1e-12f);
  #pragma unroll
  for (int j=0;j<8;j++){ float kkn = kkr[j]*inv; asv[j] = -kkn; bsv[j] = kkn*av[j]; }
  *(float4*)(dout+base)   = make_float4(dv[0],dv[1],dv[2],dv[3]);
  *(float4*)(dout+base+4) = make_float4(dv[4],dv[5],dv[6],dv[7]);
  *(uint4*)(ks+base)  = pack8(kfin);
  *(uint4*)(vs+base)  = pack8(vv);
  *(uint4*)(as_+base) = pack8(asv);
  *(uint4*)(bs+base)  = pack8(bsv);
}

// ---------------------------------------------------------------------------
// 6) the linear recurrence. Rows of S evolve independently:
//    S_t[i,:] = S_{t-1}[i,:]*(diag(d)+a b^T) + v_i k^T, so split 64 rows over
//    2 blocks/head -> 256 blocks (all CUs). Thread (ii=row 0..31, jg=colgrp
//    0..7) holds 8 fp32 state elems. 8 steps per barrier, double-buffered LDS
//    staging with register prefetch (global loads for group g+1 issued before
//    computing group g).
__global__ __launch_bounds__(256) void scan_kernel(
  const float* decayp, const u16* qb, const u16* kb, const u16* vb,
  const u16* ab, const u16* bb, float* yb)
{
  const int DEC=0, QQ=512, KK=1024, AA=1536, BB=2048, VV=2560, BUF=2816;
  __shared__ float sb[2*2816];   // 22528 B
  int blk = blockIdx.x;          // b*64 + h*2 + half
  int b    = blk >> 6;
  int h    = (blk >> 1) & 31;
  int half = blk & 1;
  int tid = threadIdx.x;
  int jg = tid & 7;              // col group (8 cols)
  int ii = tid >> 3;             // row within half (0..31)
  int row = half*32 + ii;
  int lst = tid >> 5;            // staging step 0..7
  int lc  = tid & 31;            // staging col-pair idx 0..31
  size_t hbase = ((size_t)b*TDIM)*CDIM + (size_t)h*NDIM;

  float S[8];
  #pragma unroll
  for (int e=0;e<8;e++) S[e]=0.f;

  float2 dreg; unsigned qreg, kreg, areg, breg; u16 vreg;
  auto load_group = [&](int t0){
    size_t g = hbase + (size_t)(t0+lst)*CDIM + lc*2;
    dreg = *(const float2*)(decayp + g);
    qreg = *(const unsigned*)(qb + g);
    kreg = *(const unsigned*)(kb + g);
    areg = *(const unsigned*)(ab + g);
    breg = *(const unsigned*)(bb + g);
    vreg = vb[hbase + (size_t)(t0+lst)*CDIM + half*32 + lc];
  };
  auto store_group = [&](int p){
    float* buf = &sb[p*BUF];
    *(float2*)&buf[DEC + lst*64 + lc*2] = dreg;
    *(float2*)&buf[QQ  + lst*64 + lc*2] = make_float2(b2f((u16)(qreg&0xffff)), b2f((u16)(qreg>>16)));
    *(float2*)&buf[KK  + lst*64 + lc*2] = make_float2(b2f((u16)(kreg&0xffff)), b2f((u16)(kreg>>16)));
    *(float2*)&buf[AA  + lst*64 + lc*2] = make_float2(b2f((u16)(areg&0xffff)), b2f((u16)(areg>>16)));
    *(float2*)&buf[BB  + lst*64 + lc*2] = make_float2(b2f((u16)(breg&0xffff)), b2f((u16)(breg>>16)));
    buf[VV + lst*32 + lc] = b2f(vreg);
  };

  load_group(0);
  store_group(0);
  __syncthreads();
  int p = 0;
  for (int g=0; g<120; ++g){
    if (g+1 < 120) load_group((g+1)*8);   // prefetch next group into regs
    const float* buf = &sb[p*BUF];
    #pragma unroll
    for (int s=0; s<8; ++s){
      f32x4 a0 = *(const f32x4*)&buf[AA + s*64 + jg*8];
      f32x4 a1 = *(const f32x4*)&buf[AA + s*64 + jg*8 + 4];
      float sap = S[0]*a0[0]+S[1]*a0[1]+S[2]*a0[2]+S[3]*a0[3]
                + S[4]*a1[0]+S[5]*a1[1]+S[6]*a1[2]+S[7]*a1[3];
      sap += __shfl_xor(sap,1);
      sap += __shfl_xor(sap,2);
      sap += __shfl_xor(sap,4);
      f32x4 d0 = *(const f32x4*)&buf[DEC + s*64 + jg*8];
      f32x4 d1 = *(const f32x4*)&buf[DEC + s*64 + jg*8 + 4];
      f32x4 k0 = *(const f32x4*)&buf[KK + s*64 + jg*8];
      f32x4 k1 = *(const f32x4*)&buf[KK + s*64 + jg*8 + 4];
      f32x4 b0 = *(const f32x4*)&buf[BB + s*64 + jg*8];
      f32x4 b1 = *(const f32x4*)&buf[BB + s*64 + jg*8 + 4];
      f32x4 q0 = *(const f32x4*)&buf[QQ + s*64 + jg*8];
      f32x4 q1 = *(const f32x4*)&buf[QQ + s*64 + jg*8 + 4];
      float vi = buf[VV + s*32 + ii];
      float yp = 0.f;
      #pragma unroll
      for (int e=0;e<4;e++){
        S[e]   = S[e]*d0[e]   + sap*b0[e] + vi*k0[e];
        yp    += S[e]*q0[e];
        S[e+4] = S[e+4]*d1[e] + sap*b1[e] + vi*k1[e];
        yp    += S[e+4]*q1[e];
      }
      yp += __shfl_xor(yp,1);
      yp += __shfl_xor(yp,2);
      yp += __shfl_xor(yp,4);
      if (jg==0) yb[hbase + (size_t)(g*8+s)*CDIM + row] = yp;
    }
    if (g+1 < 120) store_group(p^1);
    __syncthreads();
    p ^= 1;
  }
}

// ---------------------------------------------------------------------------
// 7) GroupNorm + bonus term + *g  -> bf16 YG (input of the final GEMM)
__global__ __launch_bounds__(256) void final_kernel(
  const float* yb, const u16* rb, const u16* ks, const u16* vs,
  const float* rk, const float* lnw, const float* lnb, const u16* gl, u16* yg)
{
  int row = blockIdx.x, tid = threadIdx.x;
  int c = tid*8;
  size_t base = (size_t)row*CDIM + c;
  float y[8], rf[8], kf[8], vf[8], rkf[8], lw[8], lb[8], gf[8];
  ld8f(yb+base, y);
  unpack8(*(const uint4*)(rb+base), rf);
  unpack8(*(const uint4*)(ks+base), kf);
  unpack8(*(const uint4*)(vs+base), vf);
  ld8f(rk+c,  rkf);   // r_k is [H*N]=[C] flat
  ld8f(lnw+c, lw);
  ld8f(lnb+c, lb);
  unpack8(*(const uint4*)(gl+base), gf);
  float sy=0.f, syy=0.f, coef=0.f;
  #pragma unroll
  for (int j=0;j<8;j++){ sy+=y[j]; syy+=y[j]*y[j]; coef += rf[j]*kf[j]*rkf[j]; }
  sy  += __shfl_xor(sy,1);  sy  += __shfl_xor(sy,2);  sy  += __shfl_xor(sy,4);
  syy += __shfl_xor(syy,1); syy += __shfl_xor(syy,2); syy += __shfl_xor(syy,4);
  coef+= __shfl_xor(coef,1);coef+= __shfl_xor(coef,2);coef+= __shfl_xor(coef,4);
  float mu  = sy*(1.f/64.f);
  float var = syy*(1.f/64.f) - mu*mu;
  float rs  = rsqrtf(var + 6.4e-4f);    // EPS_GN = 1e-5*64
  float o[8];
  #pragma unroll
  for (int j=0;j<8;j++)
    o[j] = (((y[j]-mu)*rs)*lw[j] + lb[j] + coef*vf[j]) * gf[j];
  *(uint4*)(yg+base) = pack8(o);
}

// ---------------------------------------------------------------------------
extern "C" void kernel_launch(void* const* d_in, const int* in_sizes, int n_in,
                              void* d_out, int out_size, void* d_ws, size_t ws_size,
                              hipStream_t stream)
{
  const float* x      = (const float*)d_in[0];
  const float* vfirst = (const float*)d_in[1];
  const float* c_r = (const float*)d_in[2];
  const float* c_w = (const float*)d_in[3];
  const float* c_k = (const float*)d_in[4];
  const float* c_v = (const float*)d_in[5];
  const float* c_a = (const float*)d_in[6];
  const float* c_g = (const float*)d_in[7];
  const float* w0i = (const float*)d_in[8];
  const float* w1i = (const float*)d_in[9];
  const float* w2i = (const float*)d_in[10];
  const float* a0i = (const float*)d_in[11];
  const float* a1i = (const float*)d_in[12];
  const float* a2i = (const float*)d_in[13];
  const float* v0i = (const float*)d_in[14];
  const float* v1i = (const float*)d_in[15];
  const float* v2i = (const float*)d_in[16];
  const float* g1i = (const float*)d_in[17];
  const float* g2i = (const float*)d_in[18];
  const float* kki = (const float*)d_in[19];
  const float* kai = (const float*)d_in[20];
  const float* rki = (const float*)d_in[21];
  const float* Wr  = (const float*)d_in[22];
  const float* Wk  = (const float*)d_in[23];
  const float* Wv  = (const float*)d_in[24];
  const float* Wo  = (const float*)d_in[25];
  const float* lnw = (const float*)d_in[26];
  const float* lnb = (const float*)d_in[27];

  char* ws = (char*)d_ws;
  const size_t S2 = (size_t)BT*CDIM*2;    // bf16 [BT,C] plane = 15,728,640 B
  // bf16 mix planes [0, 6*S2)  (later aliased by scan inputs)
  u16* MIXR = (u16*)(ws + 0*S2);
  u16* MIXW = (u16*)(ws + 1*S2);
  u16* MIXK = (u16*)(ws + 2*S2);
  u16* MIXV = (u16*)(ws + 3*S2);
  u16* MIXA = (u16*)(ws + 4*S2);
  u16* MIXG = (u16*)(ws + 5*S2);
  // bf16 projection outputs
  u16* RBUF = (u16*)(ws + 6*S2);
  u16* KBUF = (u16*)(ws + 7*S2);
  u16* VRAW = (u16*)(ws + 8*S2);
  // single reusable bf16 weight slot (Wr -> Wk -> Wv -> Wo, stream-ordered)
  char* WB = ws + 9*S2;
  u16* WSLOT = (u16*)WB;            // 2048*2048*2 = 8,388,608 B
  char* WT = WB + 8388608;
  u16* W1T = (u16*)(WT + 0);        // [128,2048]
  u16* A1T = (u16*)(WT + 524288);
  u16* V1T = (u16*)(WT + 1048576);
  u16* G1T = (u16*)(WT + 1572864);  // [256,2048]
  u16* W2T = (u16*)(WT + 2621440);  // [2048,128]
  u16* A2T = (u16*)(WT + 3145728);
  u16* V2T = (u16*)(WT + 3670016);
  u16* G2T = (u16*)(WT + 4194304);  // [2048,256]
  char* HB = WT + 5242880;
  u16* HW = (u16*)(HB + 0);         // [BT,128]
  u16* HA = (u16*)(HB + 983040);
  u16* HV = (u16*)(HB + 1966080);
  u16* HG = (u16*)(HB + 2949120);   // [BT,256]
  char* L2 = HB + 4915200;
  u16* WL = (u16*)(L2 + 0*S2);
  u16* AL = (u16*)(L2 + 1*S2);
  u16* VL = (u16*)(L2 + 2*S2);
  u16* GL = (u16*)(L2 + 3*S2);      // ws end = L2 + 4*S2 = 223,019,008 B (~212.7 MiB)
  // aliases (producers strictly after last consumer of the dead buffers):
  float* WDEC = (float*)(ws + 0*S2);    // fp32 decay over MIXR+MIXW
  u16* KS = (u16*)(ws + 2*S2);          // over MIXK
  u16* VS = (u16*)(ws + 3*S2);          // over MIXV
  u16* AS = (u16*)(ws + 4*S2);          // over MIXA
  u16* BS = (u16*)(ws + 5*S2);          // over MIXG
  float* YBUF = (float*)(L2 + 0*S2);    // fp32 over WL+AL
  u16* YG = (u16*)(L2 + 2*S2);          // over VL
  (void)in_sizes; (void)n_in; (void)out_size; (void)ws_size;

  // 1) transpose+pad+cvt LoRA weights
  TJobs8 tj;
  tj.j[0] = (TJob){w1i, W1T, 2048,  96, 128, 2048};
  tj.j[1] = (TJob){a1i, A1T, 2048,  96, 128, 2048};
  tj.j[2] = (TJob){v1i, V1T, 2048,  64, 128, 2048};
  tj.j[3] = (TJob){g1i, G1T, 2048, 256, 256, 2048};
  tj.j[4] = (TJob){w2i, W2T,   96, 2048, 2048, 128};
  tj.j[5] = (TJob){a2i, A2T,   96, 2048, 2048, 128};
  tj.j[6] = (TJob){v2i, V2T,   64, 2048, 2048, 128};
  tj.j[7] = (TJob){g2i, G2T,  256, 2048, 2048, 256};
  transpose_pad_kernel<<<dim3(2048,1,8), 256, 0, stream>>>(tj);

  // 2) token-shift mixes (fp32 in, bf16 out)
  mix_kernel<<<dim3(BT*CDIM/8/256), 256, 0, stream>>>(
      x, c_r, c_w, c_k, c_v, c_a, c_g, MIXR, MIXW, MIXK, MIXV, MIXA, MIXG);

  // 3) big projections r,k,v (bf16 C), weight slot reused via stream ordering
  {
    GemmJobs gj;
    cvt_kernel<<<dim3(2048), 256, 0, stream>>>(Wr, WSLOT);
    gj.j[0] = (GemmJob){MIXR, WSLOT, RBUF, 30, 16, 2048, 2048, 2048, 2048};
    gj.j[1] = gj.j[0]; gj.j[2] = gj.j[0]; gj.j[3] = gj.j[0];
    gemm_bt_kernel<u16><<<dim3(480,1,1), 256, 0, stream>>>(gj);
    cvt_kernel<<<dim3(2048), 256, 0, stream>>>(Wk, WSLOT);
    gj.j[0] = (GemmJob){MIXK, WSLOT, KBUF, 30, 16, 2048, 2048, 2048, 2048};
    gemm_bt_kernel<u16><<<dim3(480,1,1), 256, 0, stream>>>(gj);
    cvt_kernel<<<dim3(2048), 256, 0, stream>>>(Wv, WSLOT);
    gj.j[0] = (GemmJob){MIXV, WSLOT, VRAW, 30, 16, 2048, 2048, 2048, 2048};
    gemm_bt_kernel<u16><<<dim3(480,1,1), 256, 0, stream>>>(gj);
  }

  // 4) LoRA first halves (bf16 C)
  GemmJobs lj1;
  lj1.j[0] = (GemmJob){MIXW, W1T, HW, 30, 1, 2048, 2048, 2048, 128};
  lj1.j[1] = (GemmJob){MIXA, A1T, HA, 30, 1, 2048, 2048, 2048, 128};
  lj1.j[2] = (GemmJob){MIXV, V1T, HV, 30, 1, 2048, 2048, 2048, 128};
  lj1.j[3] = (GemmJob){MIXG, G1T, HG, 30, 2, 2048, 2048, 2048, 256};
  gemm_bt_kernel<u16><<<dim3(60,1,4), 256, 0, stream>>>(lj1);

  // 5) mid activations
  act_kernel<<<dim3(3840,1,2), 256, 0, stream>>>(HW, HG);

  // 6) LoRA second halves (bf16 C)
  GemmJobs lj2;
  lj2.j[0] = (GemmJob){HW, W2T, WL, 30, 16, 128, 128, 128, 2048};
  lj2.j[1] = (GemmJob){HA, A2T, AL, 30, 16, 128, 128, 128, 2048};
  lj2.j[2] = (GemmJob){HV, V2T, VL, 30, 16, 128, 128, 128, 2048};
  lj2.j[3] = (GemmJob){HG, G2T, GL, 30, 16, 256, 256, 256, 2048};
  gemm_bt_kernel<u16><<<dim3(480,1,4), 256, 0, stream>>>(lj2);

  // 7) post elementwise -> scan inputs (write into dead mix planes)
  post_kernel<<<dim3(BT), 256, 0, stream>>>(
      KBUF, VRAW, vfirst, WL, AL, VL, w0i, a0i, v0i, kki, kai,
      WDEC, KS, VS, AS, BS);

  // 8) recurrence (2 blocks per head: rows split)
  scan_kernel<<<dim3(256), 256, 0, stream>>>(
      WDEC, RBUF, KS, VS, AS, BS, YBUF);

  // 9) GroupNorm + bonus + *g -> bf16 YG
  final_kernel<<<dim3(BT), 256, 0, stream>>>(
      YBUF, RBUF, KS, VS, rki, lnw, lnb, GL, YG);

  // 10) output projection (fp32 C = d_out)
  cvt_kernel<<<dim3(2048), 256, 0, stream>>>(Wo, WSLOT);
  GemmJobs oj;
  oj.j[0] = (GemmJob){YG, WSLOT, d_out, 30, 16, 2048, 2048, 2048, 2048};
  oj.j[1] = oj.j[0]; oj.j[2] = oj.j[0]; oj.j[3] = oj.j[0];
  gemm_bt_kernel<float><<<dim3(480,1,1), 256, 0, stream>>>(oj);
}